// Round 11
// baseline (249.401 us; speedup 1.0000x reference)
//
#include <hip/hip_runtime.h>
#include <hip/hip_bf16.h>
#include <stdint.h>

// Transformer-XL relative MHA on MI355X (gfx950), bf16 MFMA pipeline.
// B=2, Q=1024, M=1024, D=1024, H=16, DH=64, K=2048.
// Evidence log:
//  - R5 failure isolated to bpermute block-selection (banned).
//  - R12: qt complement-remap; setprio; dead-tail skip. 305->287.
//  - R13: rolling R window + single barrier + fused qkvr GEMM. 287->272.
//  - R14 REFUTED (153 us): register-direct K/V/R = per-lane gathers. Reverted.
//  - R15: BDT b64 writes + merged preps. 272->261.7.
//  - R16: QKV split (-4.3 GFLOP) + 64x128 out GEMM. 261.7->249.9.
//  - R17 NEUTRAL: GEMM dbuf+prefetch ~= m99/m100 null. Kept (harmless).
//  - R18: attn glds staging + producer-side swizzle. Conflicts 6.8M->1.6M
//    (4.3x) but dur only 76.4->74.5 => LDS *issue* not binding; revised
//    model: serial BDT and Ps LDS round-trips (~300cy/iter) with 2 waves/SIMD
//    TLP are the limiter. Total 244.0.
//  - R19 (this): T15-style DEFERRED PV in k_attn: read P frags at end of
//    iter t, consume at iter t+1 (PV MFMAs overlap Ps round-trip + next
//    tile's AC/BD). V triple-buffered (stage writes Vt[(t+1)%3], deferred
//    PV reads Vt[(t-1)%3], differ by 2 mod 3 - disjoint); K dbuf + R 3-slot
//    window unchanged; epilogue PV after loop. LDS 70.1->78.3 KB (2 blk/CU).

typedef __bf16 bf16;
typedef __bf16 bf16x2 __attribute__((ext_vector_type(2)));
typedef __bf16 bf16x4 __attribute__((ext_vector_type(4)));
typedef __bf16 bf16x8 __attribute__((ext_vector_type(8)));
typedef float  f32x4  __attribute__((ext_vector_type(4)));

// ---------------------------------------------------------------- async copy
__device__ __forceinline__ void async_copy16(void* lds, const void* g) {
    auto gp = (const __attribute__((address_space(1))) void*)(uintptr_t)g;
    auto lp = (__attribute__((address_space(3))) void*)(uint32_t)(uintptr_t)lds;
    __builtin_amdgcn_global_load_lds(gp, lp, 16, 0, 0);
}

// ------------------------- 128x128 GEMM core, double-buffered prefetch (R17)
__device__ __forceinline__ void gemm128_core(
    const bf16* __restrict__ A, const bf16* __restrict__ Bt, const int Kd,
    const int m0, const int n0, bf16* As, bf16* Bs, f32x4 acc[4][4])
{
    const int tid  = threadIdx.x;
    const int lane = tid & 63;
    const int wave = tid >> 6;
    const int wr   = (wave >> 1) * 64;
    const int wc   = (wave & 1) * 64;
    const int lr   = lane & 15;
    const int q4   = lane >> 4;

#pragma unroll
    for (int i = 0; i < 4; ++i)
#pragma unroll
        for (int j = 0; j < 4; ++j) {
            acc[i][j][0] = 0.f; acc[i][j][1] = 0.f; acc[i][j][2] = 0.f; acc[i][j][3] = 0.f;
        }

    auto stage = [&](int buf, int k0) {
#pragma unroll
        for (int it = 0; it < 2; ++it) {
            const int cb0   = (it * 4 + wave) * 64;   // wave-uniform chunk base
            const int chunk = cb0 + lane;
            const int row   = chunk >> 2;
            const int cg    = (chunk & 3) * 8;
            async_copy16(As + buf * 4096 + cb0 * 8, A  + (size_t)(m0 + row) * Kd + k0 + cg);
            async_copy16(Bs + buf * 4096 + cb0 * 8, Bt + (size_t)(n0 + row) * Kd + k0 + cg);
        }
    };

    const int NT = Kd >> 5;
    stage(0, 0);
    __syncthreads();                       // tile 0 staged

    for (int t = 0; t < NT; ++t) {
        const int buf = t & 1;
        if (t + 1 < NT) stage(buf ^ 1, (t + 1) * 32);   // prefetch next step

        const bf16* Ab = As + buf * 4096;
        const bf16* Bb = Bs + buf * 4096;
        bf16x8 af[4], bfr[4];
#pragma unroll
        for (int rb = 0; rb < 4; ++rb)
            af[rb] = *(const bf16x8*)&Ab[(wr + rb * 16 + lr) * 32 + q4 * 8];
#pragma unroll
        for (int cb = 0; cb < 4; ++cb)
            bfr[cb] = *(const bf16x8*)&Bb[(wc + cb * 16 + lr) * 32 + q4 * 8];
#pragma unroll
        for (int rb = 0; rb < 4; ++rb)
#pragma unroll
            for (int cb = 0; cb < 4; ++cb)
                acc[rb][cb] = __builtin_amdgcn_mfma_f32_16x16x32_bf16(af[rb], bfr[cb], acc[rb][cb], 0, 0, 0);
        __syncthreads();                   // next tile staged; this buf free
    }
}

// -------------------------- 64x128 GEMM core, double-buffered prefetch (R17)
__device__ __forceinline__ void gemm64_core(
    const bf16* __restrict__ A, const bf16* __restrict__ Bt, const int Kd,
    const int m0, const int n0, bf16* As, bf16* Bs, f32x4 acc[2][4])
{
    const int tid  = threadIdx.x;
    const int lane = tid & 63;
    const int wave = tid >> 6;
    const int wr   = (wave >> 1) * 32;
    const int wc   = (wave & 1) * 64;
    const int lr   = lane & 15;
    const int q4   = lane >> 4;

#pragma unroll
    for (int i = 0; i < 2; ++i)
#pragma unroll
        for (int j = 0; j < 4; ++j) {
            acc[i][j][0] = 0.f; acc[i][j][1] = 0.f; acc[i][j][2] = 0.f; acc[i][j][3] = 0.f;
        }

    auto stage = [&](int buf, int k0) {
        {
            const int chunk = tid;
            const int row   = chunk >> 2;
            const int cg    = (chunk & 3) * 8;
            async_copy16(As + buf * 2048 + (wave * 64) * 8, A + (size_t)(m0 + row) * Kd + k0 + cg);
        }
#pragma unroll
        for (int it = 0; it < 2; ++it) {
            const int cb0   = (it * 4 + wave) * 64;
            const int chunk = cb0 + lane;
            const int row   = chunk >> 2;
            const int cg    = (chunk & 3) * 8;
            async_copy16(Bs + buf * 4096 + cb0 * 8, Bt + (size_t)(n0 + row) * Kd + k0 + cg);
        }
    };

    const int NT = Kd >> 5;
    stage(0, 0);
    __syncthreads();

    for (int t = 0; t < NT; ++t) {
        const int buf = t & 1;
        if (t + 1 < NT) stage(buf ^ 1, (t + 1) * 32);

        const bf16* Ab = As + buf * 2048;
        const bf16* Bb = Bs + buf * 4096;
        bf16x8 af[2], bfr[4];
#pragma unroll
        for (int rb = 0; rb < 2; ++rb)
            af[rb] = *(const bf16x8*)&Ab[(wr + rb * 16 + lr) * 32 + q4 * 8];
#pragma unroll
        for (int cb = 0; cb < 4; ++cb)
            bfr[cb] = *(const bf16x8*)&Bb[(wc + cb * 16 + lr) * 32 + q4 * 8];
#pragma unroll
        for (int rb = 0; rb < 2; ++rb)
#pragma unroll
            for (int cb = 0; cb < 4; ++cb)
                acc[rb][cb] = __builtin_amdgcn_mfma_f32_16x16x32_bf16(af[rb], bfr[cb], acc[rb][cb], 0, 0, 0);
        __syncthreads();
    }
}

// -------------------------------------------------- merged prep (all inputs)
__global__ __launch_bounds__(256) void k_prep(
    const float* __restrict__ Wqkv, const float* __restrict__ Wr,
    const float* __restrict__ Wo,
    const float* __restrict__ mem, const float* __restrict__ inp,
    const float* __restrict__ r,
    bf16* __restrict__ Wqkvt, bf16* __restrict__ Wrt, bf16* __restrict__ Wot,
    bf16* __restrict__ catb, bf16* __restrict__ rb)
{
    __shared__ float t[32][33];
    int id = blockIdx.x;
    if (id < 5120) {
        const float* in; bf16* out; int C, bx, by;
        if (id < 3072)      { in = Wqkv; out = Wqkvt; C = 3072; bx = id % 96; by = id / 96; }
        else if (id < 4096) { id -= 3072; in = Wr; out = Wrt; C = 1024; bx = id & 31; by = id >> 5; }
        else                { id -= 4096; in = Wo; out = Wot; C = 1024; bx = id & 31; by = id >> 5; }
        const int R = 1024;
        const int c0 = bx * 32, r0 = by * 32;
        const int lc = threadIdx.x & 31, lrow = threadIdx.x >> 5;
#pragma unroll
        for (int p = 0; p < 4; ++p)
            t[lrow + p * 8][lc] = in[(size_t)(r0 + lrow + p * 8) * C + c0 + lc];
        __syncthreads();
#pragma unroll
        for (int p = 0; p < 4; ++p)
            out[(size_t)(c0 + lrow + p * 8) * R + r0 + lc] = (bf16)t[lc][lrow + p * 8];
    } else if (id < 9216) {
        const int e   = ((id - 5120) * 256 + threadIdx.x) * 4;
        const int row = e >> 10, dc = e & 1023;
        const int b   = row >> 11, k = row & 2047;
        const float* src = (k < 1024) ? mem + ((size_t)b * 1024 + k) * 1024 + dc
                                      : inp + ((size_t)b * 1024 + (k - 1024)) * 1024 + dc;
        float4 f = *(const float4*)src;
        bf16x4 o; o[0] = (bf16)f.x; o[1] = (bf16)f.y; o[2] = (bf16)f.z; o[3] = (bf16)f.w;
        *(bf16x4*)&catb[e] = o;
    } else {
        const int e = ((id - 9216) * 256 + threadIdx.x) * 4;
        float4 f = *(const float4*)(r + e);
        bf16x4 o; o[0] = (bf16)f.x; o[1] = (bf16)f.y; o[2] = (bf16)f.z; o[3] = (bf16)f.w;
        *(bf16x4*)&rb[e] = o;
    }
}

// ------------------------------------------------- fused KV + Q + R GEMM
// hk/hvT/hr written PRE-SWIZZLED for the attn LDS tiles (R18):
//   hk/hr: element col d' = d ^ ((k&7)<<3)
//   hvT:   element col k' = (k&~63) | ((k&63) ^ ((d&7)<<3))
__global__ __launch_bounds__(256) void k_gemm_qkvr(
    const bf16* __restrict__ catb, const bf16* __restrict__ Wqkvt,
    const float* __restrict__ b_qkv, const float* __restrict__ u, const float* __restrict__ v,
    const bf16* __restrict__ rb_, const bf16* __restrict__ Wrt,
    const float* __restrict__ b_r,
    bf16* __restrict__ hq_u, bf16* __restrict__ hq_v,
    bf16* __restrict__ hk, bf16* __restrict__ hvT, bf16* __restrict__ hr)
{
    __shared__ bf16 lds[4 * 128 * 32];
    f32x4 acc[4][4];
    const int lane = threadIdx.x & 63, wave = threadIdx.x >> 6;
    const int wr = (wave >> 1) * 64, wc = (wave & 1) * 64;
    const int lr = lane & 15, q4 = lane >> 4;
    const int y = blockIdx.y;

    if (y < 16) {                       // ---- KV part
        const int m0 = blockIdx.x * 128;
        const int n0 = 1024 + y * 128;
        gemm128_core(catb, Wqkvt, 1024, m0, n0, lds, lds + 2 * 4096, acc);
#pragma unroll
        for (int rb = 0; rb < 4; ++rb) {
#pragma unroll
            for (int cb = 0; cb < 4; ++cb) {
                const int col  = n0 + wc + cb * 16 + lr;
                const int part = col >> 10;             // 1 or 2
                const int hd   = col & 1023;
                const int h    = hd >> 6, d = hd & 63;
                const float bcol = b_qkv[col];
#pragma unroll
                for (int r = 0; r < 4; ++r) {
                    const int row = m0 + wr + rb * 16 + q4 * 4 + r;
                    const int b   = row >> 11, k = row & 2047;
                    const float val = acc[rb][cb][r] + bcol;
                    if (part == 1) {
                        const int ks = (k & ~63) | ((k & 63) ^ ((d & 7) << 3));
                        hvT[(((size_t)(b * 16 + h)) * 64 + d) * 2048 + ks] = (bf16)val;
                    } else {
                        const int ds = d ^ ((k & 7) << 3);
                        hk[(((size_t)(b * 16 + h)) * 2048 + k) * 64 + ds] = (bf16)val;
                    }
                }
            }
        }
    } else if (y < 20) {                // ---- Q part (input rows only)
        const int linear = (y - 16) * 32 + blockIdx.x;   // [0,128)
        const int n0 = (linear & 7) * 128;
        const int mi = linear >> 3;                       // [0,16)
        const int m0 = (mi >> 3) * 2048 + 1024 + (mi & 7) * 128;
        gemm128_core(catb, Wqkvt, 1024, m0, n0, lds, lds + 2 * 4096, acc);
#pragma unroll
        for (int rb = 0; rb < 4; ++rb) {
#pragma unroll
            for (int cb = 0; cb < 4; ++cb) {
                const int col = n0 + wc + cb * 16 + lr;   // [0,1024)
                const int h = col >> 6, d = col & 63;
                const float bcol = b_qkv[col];
                const float uc = u[col], vc = v[col];
#pragma unroll
                for (int r = 0; r < 4; ++r) {
                    const int row = m0 + wr + rb * 16 + q4 * 4 + r;
                    const int b   = row >> 11, k = row & 2047;   // k in [1024,2048)
                    const float val = acc[rb][cb][r] + bcol;
                    const size_t o = (((size_t)(b * 16 + h)) * 1024 + (k - 1024)) * 64 + d;
                    hq_u[o] = (bf16)(val + uc);
                    hq_v[o] = (bf16)(val + vc);
                }
            }
        }
    } else {                            // ---- R GEMM
        const int m0 = blockIdx.x * 128;
        const int n0 = (y - 20) * 128;
        gemm128_core(rb_, Wrt, 1024, m0, n0, lds, lds + 2 * 4096, acc);
#pragma unroll
        for (int rb = 0; rb < 4; ++rb) {
#pragma unroll
            for (int cb = 0; cb < 4; ++cb) {
                const int col = n0 + wc + cb * 16 + lr;
                const int h = col >> 6, d = col & 63;
                const float bcol = b_r[col];
#pragma unroll
                for (int r = 0; r < 4; ++r) {
                    const int row = m0 + wr + rb * 16 + q4 * 4 + r;
                    const int b = row >> 11, k = row & 2047;
                    const int ds = d ^ ((k & 7) << 3);
                    hr[(((size_t)(b * 16 + h)) * 2048 + k) * 64 + ds] = (bf16)(acc[rb][cb][r] + bcol);
                }
            }
        }
    }
}

// -------------------------------------------------- out GEMM (64x128 tiles)
__global__ __launch_bounds__(256) void k_gemm_out(
    const bf16* __restrict__ attn, const bf16* __restrict__ Wt,
    const float* __restrict__ bias, float* __restrict__ out)
{
    __shared__ bf16 lds[2 * 2048 + 2 * 4096];
    f32x4 acc[2][4];
    const int m0 = blockIdx.x * 64, n0 = blockIdx.y * 128;
    gemm64_core(attn, Wt, 1024, m0, n0, lds, lds + 2 * 2048, acc);

    const int lane = threadIdx.x & 63, wave = threadIdx.x >> 6;
    const int wr = (wave >> 1) * 32, wc = (wave & 1) * 64;
    const int lr = lane & 15, q4 = lane >> 4;
#pragma unroll
    for (int rb = 0; rb < 2; ++rb) {
#pragma unroll
        for (int cb = 0; cb < 4; ++cb) {
            const int col = n0 + wc + cb * 16 + lr;
            const float bcol = bias[col];
#pragma unroll
            for (int r = 0; r < 4; ++r) {
                const int row = m0 + wr + rb * 16 + q4 * 4 + r;
                out[(size_t)row * 1024 + col] = acc[rb][cb][r] + bcol;
            }
        }
    }
}

// ------- fused attention (R19: glds staging + swizzle + DEFERRED PV)
// Per iter t: stage K(t+1)->Ks[(t+1)&1], V(t+1)->Vt[(t+1)%3], R(mt+2)->s2;
// AC(t), BD(t), scores(t), read P-frags(t); PV for tile t-1 from Vt[(t-1)%3]
// (P frags carried in regs across the barrier). Epilogue: PV(nt-1).
// Hazards: stage targets {Ks[(t+1)&1], Vt[(t+1)%3], Rs s2} vs reads
// {Ks[t&1], Vt[(t-1)%3], Rs s0,s1} - all disjoint ((t+1)-(t-1)=2 mod 3).
// V slot x%3 overwritten at iter x+2 > consumption iter x+1. LDS:
// Ks 16384 + Vt 24576 + Rs 24576 + U 12800 = 78336 B => 2 blocks/CU.
__global__ __launch_bounds__(256) void k_attn(
    const bf16* __restrict__ hq_u, const bf16* __restrict__ hq_v,
    const bf16* __restrict__ hk, const bf16* __restrict__ hvT,
    const bf16* __restrict__ hr, bf16* __restrict__ attn)
{
    __shared__ bf16 Ks[2][64][64];     // K tile [k][d-swz], double-buffered
    __shared__ bf16 Vt[3][64][64];     // V tile [d][k-swz], TRIPLE-buffered
    __shared__ bf16 Rs[192][64];       // R rolling window: 3 slots x 64 rows
    __shared__ bf16 U[4][1600];        // per-wave: BDT [80][20] / Ps [16][76]

    const int bh = blockIdx.y;
    const int qt = (bh & 16) ? (15 - (int)blockIdx.x) : (int)blockIdx.x;
    const int q0 = qt * 64;
    const int tid = threadIdx.x, lane = tid & 63, wave = tid >> 6;
    const int lr = lane & 15, q4 = lane >> 4;
    bf16* Uw = &U[wave][0];

    const int nt  = 17 + qt;
    const int m0c = 15 - qt;
    const size_t kvbase = (size_t)bh * 2048 * 64;

    // staging coordinates: chunk ci0=tid -> rows [0,32); ci1=256+tid -> [32,64)
    const int r0_ = tid >> 3, c0_ = (tid & 7) * 8;
    const int r1_ = 32 + r0_, c1_ = c0_;

    auto stage_k = [&](int t, int buf) {
        const int k0 = t * 64;
        async_copy16(&Ks[buf][r0_][c0_], &hk[kvbase + (size_t)(k0 + r0_) * 64 + c0_]);
        async_copy16(&Ks[buf][r1_][c1_], &hk[kvbase + (size_t)(k0 + r1_) * 64 + c1_]);
    };
    auto stage_v = [&](int t, int slot) {
        const int k0 = t * 64;
        async_copy16(&Vt[slot][r0_][c0_], &hvT[kvbase + (size_t)r0_ * 2048 + k0 + c0_]);
        async_copy16(&Vt[slot][r1_][c1_], &hvT[kvbase + (size_t)r1_ * 2048 + k0 + c1_]);
    };
    auto stage_r = [&](int c, int slot) {   // skip OOB: stale data only feeds masked k
        if (c * 64 < 2048) {
            async_copy16(&Rs[slot * 64 + r0_][c0_], &hr[kvbase + (size_t)(c * 64 + r0_) * 64 + c0_]);
            async_copy16(&Rs[slot * 64 + r1_][c1_], &hr[kvbase + (size_t)(c * 64 + r1_) * 64 + c1_]);
        }
    };

    // Q fragments (A-operand layout: m = lane&15, k = (lane>>4)*8 + j)
    const size_t qrow = ((size_t)bh * 1024 + q0 + wave * 16 + lr) * 64;
    const bf16x8 qu0 = *(const bf16x8*)&hq_u[qrow + q4 * 8];
    const bf16x8 qu1 = *(const bf16x8*)&hq_u[qrow + 32 + q4 * 8];
    const bf16x8 qv0 = *(const bf16x8*)&hq_v[qrow + q4 * 8];
    const bf16x8 qv1 = *(const bf16x8*)&hq_v[qrow + 32 + q4 * 8];

    // swizzled fragment-read columns (match producer-side swizzle)
    const int sw  = (lr & 7) << 3;
    const int cA0 = (q4 * 8) ^ sw;
    const int cA1 = (32 + q4 * 8) ^ sw;

    f32x4 Oacc[4];
#pragma unroll
    for (int i = 0; i < 4; ++i) { Oacc[i][0] = 0.f; Oacc[i][1] = 0.f; Oacc[i][2] = 0.f; Oacc[i][3] = 0.f; }
    float lp[4] = {0.f, 0.f, 0.f, 0.f};
    bf16x8 pf0p, pf1p;                 // P fragments of previous tile

    // prologue: async-stage tile 0 + R chunks m0c, m0c+1; barrier drains vmcnt
    stage_k(0, 0);
    stage_v(0, 0);
    stage_r(m0c,     m0c % 3);
    stage_r(m0c + 1, (m0c + 1) % 3);
    __syncthreads();

    for (int t = 0; t < nt; ++t) {
        const int k0  = t * 64;
        const int mt  = m0c + t;
        const int s0  = mt % 3;
        const int s1  = (s0 + 1 == 3) ? 0 : s0 + 1;
        const int s2  = (s1 + 1 == 3) ? 0 : s1 + 1;
        const int buf = t & 1;
        const bool more = (t + 1 < nt);
        // issue next tile's async staging NOW (targets disjoint regions)
        if (more) {
            stage_k(t + 1, buf ^ 1);
            stage_v(t + 1, (t + 1) % 3);
            stage_r(mt + 2, s2);
        }

        __builtin_amdgcn_s_setprio(1);
        // ---- AC = (hq+u) @ K^T
        f32x4 S[4];
#pragma unroll
        for (int cb = 0; cb < 4; ++cb) {
            const bf16x8 kf0 = *(const bf16x8*)&Ks[buf][cb * 16 + lr][cA0];
            const bf16x8 kf1 = *(const bf16x8*)&Ks[buf][cb * 16 + lr][cA1];
            f32x4 z; z[0] = 0.f; z[1] = 0.f; z[2] = 0.f; z[3] = 0.f;
            z = __builtin_amdgcn_mfma_f32_16x16x32_bf16(qu0, kf0, z, 0, 0, 0);
            S[cb] = __builtin_amdgcn_mfma_f32_16x16x32_bf16(qu1, kf1, z, 0, 0, 0);
        }
        // ---- BD band -> transposed BDT view (stride 20), b64 writes
#pragma unroll
        for (int jbi = 0; jbi < 5; ++jbi) {
            const int jb   = jbi + 3 - wave;
            const int rrow = ((jb & 4) ? s1 : s0) * 64 + (jb & 3) * 16 + lr;
            const bf16x8 rf0 = *(const bf16x8*)&Rs[rrow][cA0];
            const bf16x8 rf1 = *(const bf16x8*)&Rs[rrow][cA1];
            f32x4 z; z[0] = 0.f; z[1] = 0.f; z[2] = 0.f; z[3] = 0.f;
            z = __builtin_amdgcn_mfma_f32_16x16x32_bf16(qv0, rf0, z, 0, 0, 0);
            z = __builtin_amdgcn_mfma_f32_16x16x32_bf16(qv1, rf1, z, 0, 0, 0);
            bf16x4 pk;
            pk[0] = (bf16)z[0]; pk[1] = (bf16)z[1]; pk[2] = (bf16)z[2]; pk[3] = (bf16)z[3];
            *(bf16x4*)&Uw[(jbi * 16 + lr) * 20 + q4 * 4] = pk;
        }

        // ---- shifted BD reads into registers (before Ps writes)
        float bdv[4][4];
#pragma unroll
        for (int cb = 0; cb < 4; ++cb)
#pragma unroll
            for (int r = 0; r < 4; ++r) {
                const int tq = q4 * 4 + r;
                bdv[cb][r] = (float)Uw[(cb * 16 + lr + 15 - tq) * 20 + tq];
            }

        // ---- scores: mask, exp, accumulate l, Ps write (stride 76)
#pragma unroll
        for (int cb = 0; cb < 4; ++cb) {
            const int k = k0 + cb * 16 + lr;
#pragma unroll
            for (int r = 0; r < 4; ++r) {
                const int q = q0 + wave * 16 + q4 * 4 + r;
                const float s = (S[cb][r] + bdv[cb][r]) * 0.125f;
                const float p = (k <= 1024 + q) ? __expf(s) : 0.f;
                lp[r] += p;
                Uw[(q4 * 4 + r) * 76 + cb * 16 + lr] = (bf16)p;
            }
        }

        // ---- read THIS tile's P fragments (round-trip overlaps deferred PV)
        const bf16x8 pf0n = *(const bf16x8*)&Uw[lr * 76 + q4 * 8];
        const bf16x8 pf1n = *(const bf16x8*)&Uw[lr * 76 + 32 + q4 * 8];

        // ---- DEFERRED PV: tile t-1 (P in regs, V in slot (t-1)%3)
        if (t > 0) {
            const int vs = (t - 1) % 3;
#pragma unroll
            for (int db = 0; db < 4; ++db) {
                const bf16x8 vf0 = *(const bf16x8*)&Vt[vs][db * 16 + lr][cA0];
                const bf16x8 vf1 = *(const bf16x8*)&Vt[vs][db * 16 + lr][cA1];
                Oacc[db] = __builtin_amdgcn_mfma_f32_16x16x32_bf16(pf0p, vf0, Oacc[db], 0, 0, 0);
                Oacc[db] = __builtin_amdgcn_mfma_f32_16x16x32_bf16(pf1p, vf1, Oacc[db], 0, 0, 0);
            }
        }
        __builtin_amdgcn_s_setprio(0);

        pf0p = pf0n; pf1p = pf1n;

        if (more) __syncthreads();     // drains vmcnt -> staged tile visible
    }

    // ---- epilogue PV: final tile nt-1 (its V slot untouched since staged)
    {
        const int vs = (nt - 1) % 3;
#pragma unroll
        for (int db = 0; db < 4; ++db) {
            const bf16x8 vf0 = *(const bf16x8*)&Vt[vs][db * 16 + lr][cA0];
            const bf16x8 vf1 = *(const bf16x8*)&Vt[vs][db * 16 + lr][cA1];
            Oacc[db] = __builtin_amdgcn_mfma_f32_16x16x32_bf16(pf0p, vf0, Oacc[db], 0, 0, 0);
            Oacc[db] = __builtin_amdgcn_mfma_f32_16x16x32_bf16(pf1p, vf1, Oacc[db], 0, 0, 0);
        }
    }

    // ---- 16-lane row-sum of l, normalize, write
#pragma unroll
    for (int off = 1; off < 16; off <<= 1)
#pragma unroll
        for (int r = 0; r < 4; ++r) lp[r] += __shfl_xor(lp[r], off, 64);

    const int b = bh >> 4, h = bh & 15;
#pragma unroll
    for (int r = 0; r < 4; ++r) {
        const float rl = 1.f / lp[r];
        const int q = q0 + wave * 16 + q4 * 4 + r;
#pragma unroll
        for (int db = 0; db < 4; ++db) {
            const int d = db * 16 + lr;
            attn[(((size_t)b * 1024 + q) * 16 + h) * 64 + d] = (bf16)(Oacc[db][r] * rl);
        }
    }
}

// ------------------------------------------------------------------ launch
extern "C" void kernel_launch(void* const* d_in, const int* in_sizes, int n_in,
                              void* d_out, int out_size, void* d_ws, size_t ws_size,
                              hipStream_t stream)
{
    const float* inputs = (const float*)d_in[0];
    const float* mem    = (const float*)d_in[1];
    const float* r      = (const float*)d_in[2];
    const float* W_qkv  = (const float*)d_in[3];
    const float* b_qkv  = (const float*)d_in[4];
    const float* W_r    = (const float*)d_in[5];
    const float* b_r    = (const float*)d_in[6];
    const float* W_o    = (const float*)d_in[7];
    const float* b_o    = (const float*)d_in[8];
    const float* u      = (const float*)d_in[9];
    const float* v      = (const float*)d_in[10];
    float* out = (float*)d_out;

    char* ws = (char*)d_ws;
    size_t off = 0;
    auto alloc = [&](size_t bytes) -> void* {
        void* p = ws + off;
        off += (bytes + 255) & ~(size_t)255;
        return p;
    };
    bf16* hq_u  = (bf16*)alloc(2ull * 16 * 1024 * 64 * 2);
    bf16* hq_v  = (bf16*)alloc(2ull * 16 * 1024 * 64 * 2);
    bf16* hk    = (bf16*)alloc(2ull * 16 * 2048 * 64 * 2);
    bf16* hvT   = (bf16*)alloc(2ull * 16 * 2048 * 64 * 2);
    bf16* hr    = (bf16*)alloc(2ull * 16 * 2048 * 64 * 2);
    bf16* attnb = (bf16*)alloc(2ull * 1024 * 1024 * 2);
    bf16* Wot   = (bf16*)alloc(1024ull * 1024 * 2);
    bf16* catb  = (bf16*)alloc(4096ull * 1024 * 2);
    bf16* rb    = (bf16*)alloc(4096ull * 1024 * 2);
    bf16* Wqkvt = (bf16*)alloc(3072ull * 1024 * 2);
    bf16* Wrt   = (bf16*)alloc(1024ull * 1024 * 2);

    k_prep<<<13312, 256, 0, stream>>>(W_qkv, W_r, W_o, mem, inputs, r,
                                      Wqkvt, Wrt, Wot, catb, rb);

    k_gemm_qkvr<<<dim3(32, 28), 256, 0, stream>>>(catb, Wqkvt, b_qkv, u, v,
                                                  rb, Wrt, b_r,
                                                  hq_u, hq_v, hk, hvT, hr);
    k_attn<<<dim3(16, 32), 256, 0, stream>>>(hq_u, hq_v, hk, hvT, hr, attnb);
    k_gemm_out<<<dim3(32, 8), 256, 0, stream>>>(attnb, Wot, b_o, out);
}

// Round 14
// 242.898 us; speedup vs baseline: 1.0268x; 1.0268x over previous
//
#include <hip/hip_runtime.h>
#include <hip/hip_bf16.h>
#include <stdint.h>

// Transformer-XL relative MHA on MI355X (gfx950), bf16 MFMA pipeline.
// B=2, Q=1024, M=1024, D=1024, H=16, DH=64, K=2048.
// Evidence log:
//  - R5 failure isolated to bpermute block-selection (banned).
//  - R12: qt complement-remap; setprio; dead-tail skip. 305->287.
//  - R13: rolling R window + single barrier + fused qkvr GEMM. 287->272.
//  - R14 REFUTED (153 us): register-direct K/V/R = per-lane gathers. Reverted.
//  - R15: BDT b64 writes + merged preps. 272->261.7.
//  - R16: QKV split (-4.3 GFLOP) + 64x128 out GEMM. 261.7->249.9.
//  - R17 NEUTRAL: GEMM dbuf+prefetch ~= m99/m100 null. Kept (harmless).
//  - R18: attn glds staging + producer swizzle. Conflicts 6.8M->1.6M; 244.0.
//  - R19 NULL/neg: deferred PV. Reverted.
//  - R20 FAILED (absmax=468 ~= output never written): hipLaunchCooperativeKernel
//    is NOT graph-capturable in this harness. Cooperative launches BANNED.
//  - R21 COMPILE FAIL: revert carried a use-before-decl helper. Lesson:
//    reverts must be byte-identical, no cleanup riders.
//  - R22 (this): exact Round-10 verified kernel (244.0 us), helper removed.

typedef __bf16 bf16;
typedef __bf16 bf16x2 __attribute__((ext_vector_type(2)));
typedef __bf16 bf16x4 __attribute__((ext_vector_type(4)));
typedef __bf16 bf16x8 __attribute__((ext_vector_type(8)));
typedef float  f32x4  __attribute__((ext_vector_type(4)));

// ---------------------------------------------------------------- async copy
__device__ __forceinline__ void async_copy16(void* lds, const void* g) {
    auto gp = (const __attribute__((address_space(1))) void*)(uintptr_t)g;
    auto lp = (__attribute__((address_space(3))) void*)(uint32_t)(uintptr_t)lds;
    __builtin_amdgcn_global_load_lds(gp, lp, 16, 0, 0);
}

// ------------------------- 128x128 GEMM core, double-buffered prefetch (R17)
__device__ __forceinline__ void gemm128_core(
    const bf16* __restrict__ A, const bf16* __restrict__ Bt, const int Kd,
    const int m0, const int n0, bf16* As, bf16* Bs, f32x4 acc[4][4])
{
    const int tid  = threadIdx.x;
    const int lane = tid & 63;
    const int wave = tid >> 6;
    const int wr   = (wave >> 1) * 64;
    const int wc   = (wave & 1) * 64;
    const int lr   = lane & 15;
    const int q4   = lane >> 4;

#pragma unroll
    for (int i = 0; i < 4; ++i)
#pragma unroll
        for (int j = 0; j < 4; ++j) {
            acc[i][j][0] = 0.f; acc[i][j][1] = 0.f; acc[i][j][2] = 0.f; acc[i][j][3] = 0.f;
        }

    auto stage = [&](int buf, int k0) {
#pragma unroll
        for (int it = 0; it < 2; ++it) {
            const int cb0   = (it * 4 + wave) * 64;   // wave-uniform chunk base
            const int chunk = cb0 + lane;
            const int row   = chunk >> 2;
            const int cg    = (chunk & 3) * 8;
            async_copy16(As + buf * 4096 + cb0 * 8, A  + (size_t)(m0 + row) * Kd + k0 + cg);
            async_copy16(Bs + buf * 4096 + cb0 * 8, Bt + (size_t)(n0 + row) * Kd + k0 + cg);
        }
    };

    const int NT = Kd >> 5;
    stage(0, 0);
    __syncthreads();                       // tile 0 staged

    for (int t = 0; t < NT; ++t) {
        const int buf = t & 1;
        if (t + 1 < NT) stage(buf ^ 1, (t + 1) * 32);   // prefetch next step

        const bf16* Ab = As + buf * 4096;
        const bf16* Bb = Bs + buf * 4096;
        bf16x8 af[4], bfr[4];
#pragma unroll
        for (int rb = 0; rb < 4; ++rb)
            af[rb] = *(const bf16x8*)&Ab[(wr + rb * 16 + lr) * 32 + q4 * 8];
#pragma unroll
        for (int cb = 0; cb < 4; ++cb)
            bfr[cb] = *(const bf16x8*)&Bb[(wc + cb * 16 + lr) * 32 + q4 * 8];
#pragma unroll
        for (int rb = 0; rb < 4; ++rb)
#pragma unroll
            for (int cb = 0; cb < 4; ++cb)
                acc[rb][cb] = __builtin_amdgcn_mfma_f32_16x16x32_bf16(af[rb], bfr[cb], acc[rb][cb], 0, 0, 0);
        __syncthreads();                   // next tile staged; this buf free
    }
}

// -------------------------- 64x128 GEMM core, double-buffered prefetch (R17)
__device__ __forceinline__ void gemm64_core(
    const bf16* __restrict__ A, const bf16* __restrict__ Bt, const int Kd,
    const int m0, const int n0, bf16* As, bf16* Bs, f32x4 acc[2][4])
{
    const int tid  = threadIdx.x;
    const int lane = tid & 63;
    const int wave = tid >> 6;
    const int wr   = (wave >> 1) * 32;
    const int wc   = (wave & 1) * 64;
    const int lr   = lane & 15;
    const int q4   = lane >> 4;

#pragma unroll
    for (int i = 0; i < 2; ++i)
#pragma unroll
        for (int j = 0; j < 4; ++j) {
            acc[i][j][0] = 0.f; acc[i][j][1] = 0.f; acc[i][j][2] = 0.f; acc[i][j][3] = 0.f;
        }

    auto stage = [&](int buf, int k0) {
        {
            const int chunk = tid;
            const int row   = chunk >> 2;
            const int cg    = (chunk & 3) * 8;
            async_copy16(As + buf * 2048 + (wave * 64) * 8, A + (size_t)(m0 + row) * Kd + k0 + cg);
        }
#pragma unroll
        for (int it = 0; it < 2; ++it) {
            const int cb0   = (it * 4 + wave) * 64;
            const int chunk = cb0 + lane;
            const int row   = chunk >> 2;
            const int cg    = (chunk & 3) * 8;
            async_copy16(Bs + buf * 4096 + cb0 * 8, Bt + (size_t)(n0 + row) * Kd + k0 + cg);
        }
    };

    const int NT = Kd >> 5;
    stage(0, 0);
    __syncthreads();

    for (int t = 0; t < NT; ++t) {
        const int buf = t & 1;
        if (t + 1 < NT) stage(buf ^ 1, (t + 1) * 32);

        const bf16* Ab = As + buf * 2048;
        const bf16* Bb = Bs + buf * 4096;
        bf16x8 af[2], bfr[4];
#pragma unroll
        for (int rb = 0; rb < 2; ++rb)
            af[rb] = *(const bf16x8*)&Ab[(wr + rb * 16 + lr) * 32 + q4 * 8];
#pragma unroll
        for (int cb = 0; cb < 4; ++cb)
            bfr[cb] = *(const bf16x8*)&Bb[(wc + cb * 16 + lr) * 32 + q4 * 8];
#pragma unroll
        for (int rb = 0; rb < 2; ++rb)
#pragma unroll
            for (int cb = 0; cb < 4; ++cb)
                acc[rb][cb] = __builtin_amdgcn_mfma_f32_16x16x32_bf16(af[rb], bfr[cb], acc[rb][cb], 0, 0, 0);
        __syncthreads();
    }
}

// -------------------------------------------------- merged prep (all inputs)
__global__ __launch_bounds__(256) void k_prep(
    const float* __restrict__ Wqkv, const float* __restrict__ Wr,
    const float* __restrict__ Wo,
    const float* __restrict__ mem, const float* __restrict__ inp,
    const float* __restrict__ r,
    bf16* __restrict__ Wqkvt, bf16* __restrict__ Wrt, bf16* __restrict__ Wot,
    bf16* __restrict__ catb, bf16* __restrict__ rb)
{
    __shared__ float t[32][33];
    int id = blockIdx.x;
    if (id < 5120) {
        const float* in; bf16* out; int C, bx, by;
        if (id < 3072)      { in = Wqkv; out = Wqkvt; C = 3072; bx = id % 96; by = id / 96; }
        else if (id < 4096) { id -= 3072; in = Wr; out = Wrt; C = 1024; bx = id & 31; by = id >> 5; }
        else                { id -= 4096; in = Wo; out = Wot; C = 1024; bx = id & 31; by = id >> 5; }
        const int R = 1024;
        const int c0 = bx * 32, r0 = by * 32;
        const int lc = threadIdx.x & 31, lrow = threadIdx.x >> 5;
#pragma unroll
        for (int p = 0; p < 4; ++p)
            t[lrow + p * 8][lc] = in[(size_t)(r0 + lrow + p * 8) * C + c0 + lc];
        __syncthreads();
#pragma unroll
        for (int p = 0; p < 4; ++p)
            out[(size_t)(c0 + lrow + p * 8) * R + r0 + lc] = (bf16)t[lc][lrow + p * 8];
    } else if (id < 9216) {
        const int e   = ((id - 5120) * 256 + threadIdx.x) * 4;
        const int row = e >> 10, dc = e & 1023;
        const int b   = row >> 11, k = row & 2047;
        const float* src = (k < 1024) ? mem + ((size_t)b * 1024 + k) * 1024 + dc
                                      : inp + ((size_t)b * 1024 + (k - 1024)) * 1024 + dc;
        float4 f = *(const float4*)src;
        bf16x4 o; o[0] = (bf16)f.x; o[1] = (bf16)f.y; o[2] = (bf16)f.z; o[3] = (bf16)f.w;
        *(bf16x4*)&catb[e] = o;
    } else {
        const int e = ((id - 9216) * 256 + threadIdx.x) * 4;
        float4 f = *(const float4*)(r + e);
        bf16x4 o; o[0] = (bf16)f.x; o[1] = (bf16)f.y; o[2] = (bf16)f.z; o[3] = (bf16)f.w;
        *(bf16x4*)&rb[e] = o;
    }
}

// ------------------------------------------------- fused KV + Q + R GEMM
// hk/hvT/hr written PRE-SWIZZLED for the attn LDS tiles (R18):
//   hk/hr: element col d' = d ^ ((k&7)<<3)
//   hvT:   element col k' = (k&~63) | ((k&63) ^ ((d&7)<<3))
__global__ __launch_bounds__(256) void k_gemm_qkvr(
    const bf16* __restrict__ catb, const bf16* __restrict__ Wqkvt,
    const float* __restrict__ b_qkv, const float* __restrict__ u, const float* __restrict__ v,
    const bf16* __restrict__ rb_, const bf16* __restrict__ Wrt,
    const float* __restrict__ b_r,
    bf16* __restrict__ hq_u, bf16* __restrict__ hq_v,
    bf16* __restrict__ hk, bf16* __restrict__ hvT, bf16* __restrict__ hr)
{
    __shared__ bf16 lds[4 * 128 * 32];
    f32x4 acc[4][4];
    const int lane = threadIdx.x & 63, wave = threadIdx.x >> 6;
    const int wr = (wave >> 1) * 64, wc = (wave & 1) * 64;
    const int lr = lane & 15, q4 = lane >> 4;
    const int y = blockIdx.y;

    if (y < 16) {                       // ---- KV part
        const int m0 = blockIdx.x * 128;
        const int n0 = 1024 + y * 128;
        gemm128_core(catb, Wqkvt, 1024, m0, n0, lds, lds + 2 * 4096, acc);
#pragma unroll
        for (int rb = 0; rb < 4; ++rb) {
#pragma unroll
            for (int cb = 0; cb < 4; ++cb) {
                const int col  = n0 + wc + cb * 16 + lr;
                const int part = col >> 10;             // 1 or 2
                const int hd   = col & 1023;
                const int h    = hd >> 6, d = hd & 63;
                const float bcol = b_qkv[col];
#pragma unroll
                for (int r = 0; r < 4; ++r) {
                    const int row = m0 + wr + rb * 16 + q4 * 4 + r;
                    const int b   = row >> 11, k = row & 2047;
                    const float val = acc[rb][cb][r] + bcol;
                    if (part == 1) {
                        const int ks = (k & ~63) | ((k & 63) ^ ((d & 7) << 3));
                        hvT[(((size_t)(b * 16 + h)) * 64 + d) * 2048 + ks] = (bf16)val;
                    } else {
                        const int ds = d ^ ((k & 7) << 3);
                        hk[(((size_t)(b * 16 + h)) * 2048 + k) * 64 + ds] = (bf16)val;
                    }
                }
            }
        }
    } else if (y < 20) {                // ---- Q part (input rows only)
        const int linear = (y - 16) * 32 + blockIdx.x;   // [0,128)
        const int n0 = (linear & 7) * 128;
        const int mi = linear >> 3;                       // [0,16)
        const int m0 = (mi >> 3) * 2048 + 1024 + (mi & 7) * 128;
        gemm128_core(catb, Wqkvt, 1024, m0, n0, lds, lds + 2 * 4096, acc);
#pragma unroll
        for (int rb = 0; rb < 4; ++rb) {
#pragma unroll
            for (int cb = 0; cb < 4; ++cb) {
                const int col = n0 + wc + cb * 16 + lr;   // [0,1024)
                const int h = col >> 6, d = col & 63;
                const float bcol = b_qkv[col];
                const float uc = u[col], vc = v[col];
#pragma unroll
                for (int r = 0; r < 4; ++r) {
                    const int row = m0 + wr + rb * 16 + q4 * 4 + r;
                    const int b   = row >> 11, k = row & 2047;   // k in [1024,2048)
                    const float val = acc[rb][cb][r] + bcol;
                    const size_t o = (((size_t)(b * 16 + h)) * 1024 + (k - 1024)) * 64 + d;
                    hq_u[o] = (bf16)(val + uc);
                    hq_v[o] = (bf16)(val + vc);
                }
            }
        }
    } else {                            // ---- R GEMM
        const int m0 = blockIdx.x * 128;
        const int n0 = (y - 20) * 128;
        gemm128_core(rb_, Wrt, 1024, m0, n0, lds, lds + 2 * 4096, acc);
#pragma unroll
        for (int rb = 0; rb < 4; ++rb) {
#pragma unroll
            for (int cb = 0; cb < 4; ++cb) {
                const int col = n0 + wc + cb * 16 + lr;
                const int h = col >> 6, d = col & 63;
                const float bcol = b_r[col];
#pragma unroll
                for (int r = 0; r < 4; ++r) {
                    const int row = m0 + wr + rb * 16 + q4 * 4 + r;
                    const int b = row >> 11, k = row & 2047;
                    const int ds = d ^ ((k & 7) << 3);
                    hr[(((size_t)(b * 16 + h)) * 2048 + k) * 64 + ds] = (bf16)(acc[rb][cb][r] + bcol);
                }
            }
        }
    }
}

// -------------------------------------------------- out GEMM (64x128 tiles)
__global__ __launch_bounds__(256) void k_gemm_out(
    const bf16* __restrict__ attn, const bf16* __restrict__ Wt,
    const float* __restrict__ bias, float* __restrict__ out)
{
    __shared__ bf16 lds[2 * 2048 + 2 * 4096];
    f32x4 acc[2][4];
    const int m0 = blockIdx.x * 64, n0 = blockIdx.y * 128;
    gemm64_core(attn, Wt, 1024, m0, n0, lds, lds + 2 * 2048, acc);

    const int lane = threadIdx.x & 63, wave = threadIdx.x >> 6;
    const int wr = (wave >> 1) * 32, wc = (wave & 1) * 64;
    const int lr = lane & 15, q4 = lane >> 4;
#pragma unroll
    for (int rb = 0; rb < 2; ++rb) {
#pragma unroll
        for (int cb = 0; cb < 4; ++cb) {
            const int col = n0 + wc + cb * 16 + lr;
            const float bcol = bias[col];
#pragma unroll
            for (int r = 0; r < 4; ++r) {
                const int row = m0 + wr + rb * 16 + q4 * 4 + r;
                out[(size_t)row * 1024 + col] = acc[rb][cb][r] + bcol;
            }
        }
    }
}

// ---------------- fused attention (R18: global_load_lds staging, swizzled)
// Unpadded [64][64] tiles, linear LDS dest for async staging; fragment reads
// XOR-swizzled (col ^ (lr&7)<<3) to match producer-side swizzle. One barrier
// per tile. Stale R rows (j>=2048) only feed masked k. LDS 70144 B.
__global__ __launch_bounds__(256) void k_attn(
    const bf16* __restrict__ hq_u, const bf16* __restrict__ hq_v,
    const bf16* __restrict__ hk, const bf16* __restrict__ hvT,
    const bf16* __restrict__ hr, bf16* __restrict__ attn)
{
    __shared__ bf16 Ks[2][64][64];     // K tile [k][d-swz], double-buffered
    __shared__ bf16 Vt[2][64][64];     // V tile [d][k-swz], double-buffered
    __shared__ bf16 Rs[192][64];       // R rolling window: 3 slots x 64 rows
    __shared__ bf16 U[4][1600];        // per-wave: BDT [80][20] / Ps [16][76]

    const int bh = blockIdx.y;
    const int qt = (bh & 16) ? (15 - (int)blockIdx.x) : (int)blockIdx.x;
    const int q0 = qt * 64;
    const int tid = threadIdx.x, lane = tid & 63, wave = tid >> 6;
    const int lr = lane & 15, q4 = lane >> 4;
    bf16* Uw = &U[wave][0];

    const int nt  = 17 + qt;
    const int m0c = 15 - qt;
    const size_t kvbase = (size_t)bh * 2048 * 64;

    // staging coordinates: chunk ci0=tid -> rows [0,32); ci1=256+tid -> [32,64)
    const int r0_ = tid >> 3, c0_ = (tid & 7) * 8;
    const int r1_ = 32 + r0_, c1_ = c0_;

    auto stage_kv = [&](int t, int buf) {
        const int k0 = t * 64;
        async_copy16(&Ks[buf][r0_][c0_], &hk [kvbase + (size_t)(k0 + r0_) * 64 + c0_]);
        async_copy16(&Ks[buf][r1_][c1_], &hk [kvbase + (size_t)(k0 + r1_) * 64 + c1_]);
        async_copy16(&Vt[buf][r0_][c0_], &hvT[kvbase + (size_t)r0_ * 2048 + k0 + c0_]);
        async_copy16(&Vt[buf][r1_][c1_], &hvT[kvbase + (size_t)r1_ * 2048 + k0 + c1_]);
    };
    auto stage_r = [&](int c, int slot) {   // skip OOB: stale data only feeds masked k
        if (c * 64 < 2048) {
            async_copy16(&Rs[slot * 64 + r0_][c0_], &hr[kvbase + (size_t)(c * 64 + r0_) * 64 + c0_]);
            async_copy16(&Rs[slot * 64 + r1_][c1_], &hr[kvbase + (size_t)(c * 64 + r1_) * 64 + c1_]);
        }
    };

    // Q fragments (A-operand layout: m = lane&15, k = (lane>>4)*8 + j)
    const size_t qrow = ((size_t)bh * 1024 + q0 + wave * 16 + lr) * 64;
    const bf16x8 qu0 = *(const bf16x8*)&hq_u[qrow + q4 * 8];
    const bf16x8 qu1 = *(const bf16x8*)&hq_u[qrow + 32 + q4 * 8];
    const bf16x8 qv0 = *(const bf16x8*)&hq_v[qrow + q4 * 8];
    const bf16x8 qv1 = *(const bf16x8*)&hq_v[qrow + 32 + q4 * 8];

    // swizzled fragment-read columns (match producer-side swizzle)
    const int sw  = (lr & 7) << 3;
    const int cA0 = (q4 * 8) ^ sw;
    const int cA1 = (32 + q4 * 8) ^ sw;

    f32x4 Oacc[4];
#pragma unroll
    for (int i = 0; i < 4; ++i) { Oacc[i][0] = 0.f; Oacc[i][1] = 0.f; Oacc[i][2] = 0.f; Oacc[i][3] = 0.f; }
    float lp[4] = {0.f, 0.f, 0.f, 0.f};

    // prologue: async-stage tile 0 + R chunks m0c, m0c+1; barrier drains vmcnt
    stage_kv(0, 0);
    stage_r(m0c,     m0c % 3);
    stage_r(m0c + 1, (m0c + 1) % 3);
    __syncthreads();

    for (int t = 0; t < nt; ++t) {
        const int k0  = t * 64;
        const int mt  = m0c + t;
        const int s0  = mt % 3;
        const int s1  = (s0 + 1 == 3) ? 0 : s0 + 1;
        const int s2  = (s1 + 1 == 3) ? 0 : s1 + 1;
        const int buf = t & 1;
        const bool more = (t + 1 < nt);
        // issue next tile's async staging NOW (targets disjoint regions)
        if (more) { stage_kv(t + 1, buf ^ 1); stage_r(mt + 2, s2); }

        __builtin_amdgcn_s_setprio(1);
        // ---- AC = (hq+u) @ K^T
        f32x4 S[4];
#pragma unroll
        for (int cb = 0; cb < 4; ++cb) {
            const bf16x8 kf0 = *(const bf16x8*)&Ks[buf][cb * 16 + lr][cA0];
            const bf16x8 kf1 = *(const bf16x8*)&Ks[buf][cb * 16 + lr][cA1];
            f32x4 z; z[0] = 0.f; z[1] = 0.f; z[2] = 0.f; z[3] = 0.f;
            z = __builtin_amdgcn_mfma_f32_16x16x32_bf16(qu0, kf0, z, 0, 0, 0);
            S[cb] = __builtin_amdgcn_mfma_f32_16x16x32_bf16(qu1, kf1, z, 0, 0, 0);
        }
        // ---- BD band -> transposed BDT view (stride 20), b64 writes
#pragma unroll
        for (int jbi = 0; jbi < 5; ++jbi) {
            const int jb   = jbi + 3 - wave;
            const int rrow = ((jb & 4) ? s1 : s0) * 64 + (jb & 3) * 16 + lr;
            const bf16x8 rf0 = *(const bf16x8*)&Rs[rrow][cA0];
            const bf16x8 rf1 = *(const bf16x8*)&Rs[rrow][cA1];
            f32x4 z; z[0] = 0.f; z[1] = 0.f; z[2] = 0.f; z[3] = 0.f;
            z = __builtin_amdgcn_mfma_f32_16x16x32_bf16(qv0, rf0, z, 0, 0, 0);
            z = __builtin_amdgcn_mfma_f32_16x16x32_bf16(qv1, rf1, z, 0, 0, 0);
            bf16x4 pk;
            pk[0] = (bf16)z[0]; pk[1] = (bf16)z[1]; pk[2] = (bf16)z[2]; pk[3] = (bf16)z[3];
            *(bf16x4*)&Uw[(jbi * 16 + lr) * 20 + q4 * 4] = pk;
        }

        // ---- shifted BD reads into registers (before Ps writes)
        float bdv[4][4];
#pragma unroll
        for (int cb = 0; cb < 4; ++cb)
#pragma unroll
            for (int r = 0; r < 4; ++r) {
                const int tq = q4 * 4 + r;
                bdv[cb][r] = (float)Uw[(cb * 16 + lr + 15 - tq) * 20 + tq];
            }

        // ---- scores: mask, exp, accumulate l, Ps write (stride 76)
#pragma unroll
        for (int cb = 0; cb < 4; ++cb) {
            const int k = k0 + cb * 16 + lr;
#pragma unroll
            for (int r = 0; r < 4; ++r) {
                const int q = q0 + wave * 16 + q4 * 4 + r;
                const float s = (S[cb][r] + bdv[cb][r]) * 0.125f;
                const float p = (k <= 1024 + q) ? __expf(s) : 0.f;
                lp[r] += p;
                Uw[(q4 * 4 + r) * 76 + cb * 16 + lr] = (bf16)p;
            }
        }

        // ---- PV
        const bf16x8 pf0 = *(const bf16x8*)&Uw[lr * 76 + q4 * 8];
        const bf16x8 pf1 = *(const bf16x8*)&Uw[lr * 76 + 32 + q4 * 8];
#pragma unroll
        for (int db = 0; db < 4; ++db) {
            const bf16x8 vf0 = *(const bf16x8*)&Vt[buf][db * 16 + lr][cA0];
            const bf16x8 vf1 = *(const bf16x8*)&Vt[buf][db * 16 + lr][cA1];
            Oacc[db] = __builtin_amdgcn_mfma_f32_16x16x32_bf16(pf0, vf0, Oacc[db], 0, 0, 0);
            Oacc[db] = __builtin_amdgcn_mfma_f32_16x16x32_bf16(pf1, vf1, Oacc[db], 0, 0, 0);
        }
        __builtin_amdgcn_s_setprio(0);

        if (more) __syncthreads();     // drains vmcnt -> staged tile visible
    }

    // ---- 16-lane row-sum of l, normalize, write
#pragma unroll
    for (int off = 1; off < 16; off <<= 1)
#pragma unroll
        for (int r = 0; r < 4; ++r) lp[r] += __shfl_xor(lp[r], off, 64);

    const int b = bh >> 4, h = bh & 15;
#pragma unroll
    for (int r = 0; r < 4; ++r) {
        const float rl = 1.f / lp[r];
        const int q = q0 + wave * 16 + q4 * 4 + r;
#pragma unroll
        for (int db = 0; db < 4; ++db) {
            const int d = db * 16 + lr;
            attn[(((size_t)b * 1024 + q) * 16 + h) * 64 + d] = (bf16)(Oacc[db][r] * rl);
        }
    }
}

// ------------------------------------------------------------------ launch
extern "C" void kernel_launch(void* const* d_in, const int* in_sizes, int n_in,
                              void* d_out, int out_size, void* d_ws, size_t ws_size,
                              hipStream_t stream)
{
    const float* inputs = (const float*)d_in[0];
    const float* mem    = (const float*)d_in[1];
    const float* r      = (const float*)d_in[2];
    const float* W_qkv  = (const float*)d_in[3];
    const float* b_qkv  = (const float*)d_in[4];
    const float* W_r    = (const float*)d_in[5];
    const float* b_r    = (const float*)d_in[6];
    const float* W_o    = (const float*)d_in[7];
    const float* b_o    = (const float*)d_in[8];
    const float* u      = (const float*)d_in[9];
    const float* v      = (const float*)d_in[10];
    float* out = (float*)d_out;

    char* ws = (char*)d_ws;
    size_t off = 0;
    auto alloc = [&](size_t bytes) -> void* {
        void* p = ws + off;
        off += (bytes + 255) & ~(size_t)255;
        return p;
    };
    bf16* hq_u  = (bf16*)alloc(2ull * 16 * 1024 * 64 * 2);
    bf16* hq_v  = (bf16*)alloc(2ull * 16 * 1024 * 64 * 2);
    bf16* hk    = (bf16*)alloc(2ull * 16 * 2048 * 64 * 2);
    bf16* hvT   = (bf16*)alloc(2ull * 16 * 2048 * 64 * 2);
    bf16* hr    = (bf16*)alloc(2ull * 16 * 2048 * 64 * 2);
    bf16* attnb = (bf16*)alloc(2ull * 1024 * 1024 * 2);
    bf16* Wot   = (bf16*)alloc(1024ull * 1024 * 2);
    bf16* catb  = (bf16*)alloc(4096ull * 1024 * 2);
    bf16* rb    = (bf16*)alloc(4096ull * 1024 * 2);
    bf16* Wqkvt = (bf16*)alloc(3072ull * 1024 * 2);
    bf16* Wrt   = (bf16*)alloc(1024ull * 1024 * 2);

    k_prep<<<13312, 256, 0, stream>>>(W_qkv, W_r, W_o, mem, inputs, r,
                                      Wqkvt, Wrt, Wot, catb, rb);

    k_gemm_qkvr<<<dim3(32, 28), 256, 0, stream>>>(catb, Wqkvt, b_qkv, u, v,
                                                  rb, Wrt, b_r,
                                                  hq_u, hq_v, hk, hvT, hr);
    k_attn<<<dim3(16, 32), 256, 0, stream>>>(hq_u, hq_v, hk, hvT, hr, attnb);
    k_gemm_out<<<dim3(32, 8), 256, 0, stream>>>(attnb, Wot, b_o, out);
}